// Round 1
// baseline (399.117 us; speedup 1.0000x reference)
//
#include <hip/hip_runtime.h>
#include <math.h>

typedef unsigned short u16;
typedef short short8 __attribute__((ext_vector_type(8)));
typedef float f32x4 __attribute__((ext_vector_type(4)));

#define NH   12
#define SEQ  2048
#define CDIM 768
#define BATCH 4

__device__ __forceinline__ u16 f2bf(float f) {
  unsigned u = __float_as_uint(f);
  u += 0x7fffu + ((u >> 16) & 1u);   // RNE
  return (u16)(u >> 16);
}

// ---------------- fp32 -> bf16 convert ----------------
__global__ __launch_bounds__(256) void cvt_f32_bf16(const float* __restrict__ in,
                                                    u16* __restrict__ out, int n) {
  int i = (blockIdx.x * 256 + threadIdx.x) * 4;
  if (i < n) {
    float4 f = *(const float4*)(in + i);
    ushort4 o;
    o.x = f2bf(f.x); o.y = f2bf(f.y); o.z = f2bf(f.z); o.w = f2bf(f.w);
    *(ushort4*)(out + i) = o;
  }
}

// ---------------- NT GEMM: C[M,N] = A[M,K] @ B[N,K]^T, bf16 in, fp32 acc ----
// MODE 0: store bf16 to q layout [B,H,N,D]
// MODE 1: cols [0,768)->k buf, [768,1536)->v buf, layout [B,H,N,D]
// MODE 2: fp32 out[M,N] = acc + bias[n]
template<int MODE>
__global__ __launch_bounds__(256) void gemm_nt(
    const u16* __restrict__ A, const u16* __restrict__ B,
    u16* __restrict__ out0, u16* __restrict__ out1,
    float* __restrict__ outf, const float* __restrict__ bias,
    int M, int N, int K)
{
  constexpr int LD = 40;                       // 32 + 8 pad (keeps 16B align, breaks bank stride)
  __shared__ __align__(16) u16 As[128 * LD];
  __shared__ __align__(16) u16 Bs[128 * LD];
  const int tid = threadIdx.x;
  const int wave = tid >> 6, lane = tid & 63;
  const int quad = lane >> 4, l16 = lane & 15;
  const int row0 = blockIdx.x * 128, col0 = blockIdx.y * 128;
  const int wm = (wave >> 1) * 64, wn = (wave & 1) * 64;

  f32x4 acc[4][4] = {};

  for (int k0 = 0; k0 < K; k0 += 32) {
    __syncthreads();
    #pragma unroll
    for (int i = 0; i < 2; i++) {
      int ch = tid + i * 256;                  // 512 chunks of 8 per matrix
      int r = ch >> 2, cc = (ch & 3) * 8;
      *(uint4*)(&As[r * LD + cc]) = *(const uint4*)(A + (size_t)(row0 + r) * K + k0 + cc);
      *(uint4*)(&Bs[r * LD + cc]) = *(const uint4*)(B + (size_t)(col0 + r) * K + k0 + cc);
    }
    __syncthreads();
    short8 af[4], bfr[4];
    #pragma unroll
    for (int mt = 0; mt < 4; mt++)
      af[mt] = *(const short8*)&As[(wm + mt * 16 + l16) * LD + quad * 8];
    #pragma unroll
    for (int nt = 0; nt < 4; nt++)
      bfr[nt] = *(const short8*)&Bs[(wn + nt * 16 + l16) * LD + quad * 8];
    #pragma unroll
    for (int mt = 0; mt < 4; mt++)
      #pragma unroll
      for (int nt = 0; nt < 4; nt++)
        acc[mt][nt] = __builtin_amdgcn_mfma_f32_16x16x32_bf16(af[mt], bfr[nt], acc[mt][nt], 0, 0, 0);
  }

  // epilogue: C layout col=lane&15, row=quad*4+reg
  #pragma unroll
  for (int mt = 0; mt < 4; mt++)
  #pragma unroll
  for (int nt = 0; nt < 4; nt++)
  #pragma unroll
  for (int r = 0; r < 4; r++) {
    int gm = row0 + wm + mt * 16 + quad * 4 + r;
    int gn = col0 + wn + nt * 16 + l16;
    float v = acc[mt][nt][r];
    if (MODE == 0) {
      int b = gm >> 11, n = gm & 2047;
      int h = gn >> 6, d = gn & 63;
      out0[(((size_t)(b * NH + h)) * SEQ + n) * 64 + d] = f2bf(v);
    } else if (MODE == 1) {
      int b = gm >> 11, n = gm & 2047;
      int s = (gn >= CDIM) ? 1 : 0;
      int c = gn - s * CDIM;
      int h = c >> 6, d = c & 63;
      u16* dst = s ? out1 : out0;
      dst[(((size_t)(b * NH + h)) * SEQ + n) * 64 + d] = f2bf(v);
    } else {
      outf[(size_t)gm * N + gn] = v + bias[gn];
    }
  }
}

// ---------------- flash attention ----------------
// grid: 48 (b,h) * 16 q-tiles of 128 rows. block 256 = 4 waves, 32 Q-rows/wave.
// inner K/V tile BN=64. Q frags preloaded in registers.
__global__ __launch_bounds__(256) void attn_kernel(
    const u16* __restrict__ Q, const u16* __restrict__ Kb,
    const u16* __restrict__ Vb, const float* __restrict__ taup,
    u16* __restrict__ Ob)
{
  constexpr int LD = 72;                       // 64 + 8 pad
  __shared__ __align__(16) u16 Ks[64 * LD];
  __shared__ __align__(16) u16 Vt[64 * LD];    // transposed: Vt[d][k]
  __shared__ __align__(16) u16 Ps[128 * LD];   // per-wave 32-row private regions

  const int qt = blockIdx.x & 15;
  const int bh = blockIdx.x >> 4;              // b*NH + h
  const int b = bh / NH, h = bh % NH;
  const u16* Qp = Q + (size_t)bh * SEQ * 64;
  const u16* Kp = Kb + (size_t)bh * SEQ * 64;
  const u16* Vp = Vb + (size_t)bh * SEQ * 64;

  const int tid = threadIdx.x;
  const int wave = tid >> 6, lane = tid & 63;
  const int quad = lane >> 4, l16 = lane & 15;
  const int wm = wave * 32;

  // tau = softplus(tau_param) + 1e-6 ; fold D^-0.5 and log2(e) into logit scale
  float t = *taup;
  float sp = (t > 20.f) ? t : log1pf(expf(t));
  const float qkscale = (0.125f / (sp + 1e-6f)) * 1.44269504088896340736f;

  // preload Q fragments (A-layout: A[m=lane&15][k=quad*8+j])
  short8 qf[2][2];
  #pragma unroll
  for (int mt = 0; mt < 2; mt++)
    #pragma unroll
    for (int ks = 0; ks < 2; ks++)
      qf[mt][ks] = *(const short8*)(Qp + (size_t)(qt * 128 + wm + mt * 16 + l16) * 64 + ks * 32 + quad * 8);

  f32x4 oacc[2][4] = {};
  float mst[2][4], lst[2][4];
  #pragma unroll
  for (int mt = 0; mt < 2; mt++)
    #pragma unroll
    for (int r = 0; r < 4; r++) { mst[mt][r] = -1e30f; lst[mt][r] = 0.f; }

  for (int kt = 0; kt < SEQ / 64; kt++) {
    __syncthreads();                           // protect Ks/Vt from previous iter readers
    #pragma unroll
    for (int i = 0; i < 2; i++) {
      int ch = tid + i * 256;                  // 512 chunks of 8
      int r = ch >> 3, cc = (ch & 7) * 8;
      *(uint4*)(&Ks[r * LD + cc]) = *(const uint4*)(Kp + (size_t)(kt * 64 + r) * 64 + cc);
      uint4 w = *(const uint4*)(Vp + (size_t)(kt * 64 + r) * 64 + cc);
      u16 tmp[8];
      *(uint4*)tmp = w;
      #pragma unroll
      for (int j = 0; j < 8; j++) Vt[(cc + j) * LD + r] = tmp[j];
    }
    __syncthreads();

    // S = Q K^T  (32 rows x 64 cols per wave)
    f32x4 sacc[2][4] = {};
    #pragma unroll
    for (int ks = 0; ks < 2; ks++) {
      #pragma unroll
      for (int nt = 0; nt < 4; nt++) {
        short8 kf = *(const short8*)&Ks[(nt * 16 + l16) * LD + ks * 32 + quad * 8];
        #pragma unroll
        for (int mt = 0; mt < 2; mt++)
          sacc[mt][nt] = __builtin_amdgcn_mfma_f32_16x16x32_bf16(qf[mt][ks], kf, sacc[mt][nt], 0, 0, 0);
      }
    }

    // online softmax per (mt, reg) row; row group = 16 lanes (col = lane&15)
    #pragma unroll
    for (int mt = 0; mt < 2; mt++) {
      #pragma unroll
      for (int r = 0; r < 4; r++) {
        float v0 = sacc[mt][0][r] * qkscale;
        float v1 = sacc[mt][1][r] * qkscale;
        float v2 = sacc[mt][2][r] * qkscale;
        float v3 = sacc[mt][3][r] * qkscale;
        float rm = fmaxf(fmaxf(v0, v1), fmaxf(v2, v3));
        #pragma unroll
        for (int off = 1; off < 16; off <<= 1) rm = fmaxf(rm, __shfl_xor(rm, off));
        float mnew = fmaxf(mst[mt][r], rm);
        float alpha = exp2f(mst[mt][r] - mnew);
        float p0 = exp2f(v0 - mnew), p1 = exp2f(v1 - mnew);
        float p2 = exp2f(v2 - mnew), p3 = exp2f(v3 - mnew);
        float rs = (p0 + p1) + (p2 + p3);
        #pragma unroll
        for (int off = 1; off < 16; off <<= 1) rs += __shfl_xor(rs, off);
        lst[mt][r] = lst[mt][r] * alpha + rs;
        mst[mt][r] = mnew;
        #pragma unroll
        for (int dt = 0; dt < 4; dt++) oacc[mt][dt][r] *= alpha;
        int prow = wm + mt * 16 + quad * 4 + r;
        Ps[prow * LD + 0 * 16 + l16] = f2bf(p0);
        Ps[prow * LD + 1 * 16 + l16] = f2bf(p1);
        Ps[prow * LD + 2 * 16 + l16] = f2bf(p2);
        Ps[prow * LD + 3 * 16 + l16] = f2bf(p3);
      }
    }

    // O += P V   (P via LDS round-trip C->A layout; V from transposed Vt)
    #pragma unroll
    for (int ks = 0; ks < 2; ks++) {
      short8 pf[2];
      #pragma unroll
      for (int mt = 0; mt < 2; mt++)
        pf[mt] = *(const short8*)&Ps[(wm + mt * 16 + l16) * LD + ks * 32 + quad * 8];
      #pragma unroll
      for (int dt = 0; dt < 4; dt++) {
        short8 vf = *(const short8*)&Vt[(dt * 16 + l16) * LD + ks * 32 + quad * 8];
        #pragma unroll
        for (int mt = 0; mt < 2; mt++)
          oacc[mt][dt] = __builtin_amdgcn_mfma_f32_16x16x32_bf16(pf[mt], vf, oacc[mt][dt], 0, 0, 0);
      }
    }
  }

  // epilogue: O / l -> ao[b][n][h*64+d] (bf16, [B,N,C] layout for proj GEMM)
  #pragma unroll
  for (int mt = 0; mt < 2; mt++)
    #pragma unroll
    for (int r = 0; r < 4; r++) {
      float inv = 1.0f / lst[mt][r];
      int n = qt * 128 + wm + mt * 16 + quad * 4 + r;
      size_t base = ((size_t)b * SEQ + n) * CDIM + h * 64;
      #pragma unroll
      for (int dt = 0; dt < 4; dt++)
        Ob[base + dt * 16 + l16] = f2bf(oacc[mt][dt][r] * inv);
    }
}

// ---------------- launch ----------------
extern "C" void kernel_launch(void* const* d_in, const int* in_sizes, int n_in,
                              void* d_out, int out_size, void* d_ws, size_t ws_size,
                              hipStream_t stream)
{
  const float* x     = (const float*)d_in[0];
  const float* y     = (const float*)d_in[1];
  const float* Wq    = (const float*)d_in[2];
  const float* Wkv   = (const float*)d_in[3];
  const float* taup  = (const float*)d_in[4];
  const float* Wproj = (const float*)d_in[5];
  const float* bproj = (const float*)d_in[6];
  float* out = (float*)d_out;

  char* ws = (char*)d_ws;
  size_t off = 0;
  auto alloc = [&](size_t bytes) { char* p = ws + off; off += bytes; return p; };
  u16* xb   = (u16*)alloc(8192ull * 768 * 2);
  u16* yb   = (u16*)alloc(8192ull * 768 * 2);
  u16* wqb  = (u16*)alloc(768ull * 768 * 2);
  u16* wkvb = (u16*)alloc(1536ull * 768 * 2);
  u16* wpb  = (u16*)alloc(768ull * 768 * 2);
  u16* qb   = (u16*)alloc(8192ull * 768 * 2);   // [B,H,N,D]
  u16* kb   = (u16*)alloc(8192ull * 768 * 2);
  u16* vb   = (u16*)alloc(8192ull * 768 * 2);
  u16* ao   = (u16*)alloc(8192ull * 768 * 2);   // [B,N,C]
  // total ws: ~80.2 MB

  cvt_f32_bf16<<<8192 * 768 / 1024, 256, 0, stream>>>(x, xb, 8192 * 768);
  cvt_f32_bf16<<<8192 * 768 / 1024, 256, 0, stream>>>(y, yb, 8192 * 768);
  cvt_f32_bf16<<<768 * 768 / 1024, 256, 0, stream>>>(Wq, wqb, 768 * 768);
  cvt_f32_bf16<<<1536 * 768 / 1024, 256, 0, stream>>>(Wkv, wkvb, 1536 * 768);
  cvt_f32_bf16<<<768 * 768 / 1024, 256, 0, stream>>>(Wproj, wpb, 768 * 768);

  gemm_nt<0><<<dim3(64, 6), 256, 0, stream>>>(xb, wqb, qb, nullptr, nullptr, nullptr, 8192, 768, 768);
  gemm_nt<1><<<dim3(64, 12), 256, 0, stream>>>(yb, wkvb, kb, vb, nullptr, nullptr, 8192, 1536, 768);
  attn_kernel<<<dim3(48 * 16), 256, 0, stream>>>(qb, kb, vb, taup, ao);
  gemm_nt<2><<<dim3(64, 6), 256, 0, stream>>>(ao, wpb, nullptr, nullptr, out, bproj, 8192, 768, 768);
}

// Round 3
// 300.587 us; speedup vs baseline: 1.3278x; 1.3278x over previous
//
#include <hip/hip_runtime.h>
#include <math.h>

typedef unsigned short u16;
typedef unsigned int u32;
typedef short short8 __attribute__((ext_vector_type(8)));
typedef float f32x4 __attribute__((ext_vector_type(4)));

#define NH   12
#define SEQ  2048
#define CDIM 768

__device__ __forceinline__ u16 f2bf(float f) {
  unsigned u = __float_as_uint(f);
  u += 0x7fffu + ((u >> 16) & 1u);   // RNE
  return (u16)(u >> 16);
}

// ---------------- fp32 -> bf16 convert ----------------
__global__ __launch_bounds__(256) void cvt_f32_bf16(const float* __restrict__ in,
                                                    u16* __restrict__ out, int n) {
  int i = (blockIdx.x * 256 + threadIdx.x) * 4;
  if (i < n) {
    float4 f = *(const float4*)(in + i);
    ushort4 o;
    o.x = f2bf(f.x); o.y = f2bf(f.y); o.z = f2bf(f.z); o.w = f2bf(f.w);
    *(ushort4*)(out + i) = o;
  }
}

// ---------------- NT GEMM: C[M,N] = A[M,K] @ B[N,K]^T, bf16 in, fp32 acc ----
// Tile: 128(M) x 64(N), 4 waves in 2x2, wave tile 64x32.
// MODE 0: out0 = q layout [B,H,N,D], scaled by qkscale(tau)
// MODE 1: cols [0,768)->k [B,H,N,D]; [768,1536)->v TRANSPOSED [B,H,D,N]
// MODE 2: fp32 out[M,N] = acc + bias[n]
template<int MODE>
__global__ __launch_bounds__(256, 4) void gemm_nt(
    const u16* __restrict__ A, const u16* __restrict__ B,
    u16* __restrict__ out0, u16* __restrict__ out1,
    float* __restrict__ outf, const float* __restrict__ bias,
    const float* __restrict__ taup, int M, int N, int K)
{
  constexpr int LD = 40;                       // 32 + 8 pad
  __shared__ __align__(16) u16 As[128 * LD];
  __shared__ __align__(16) u16 Bs[64 * LD];
  const int tid = threadIdx.x;
  const int wave = tid >> 6, lane = tid & 63;
  const int quad = lane >> 4, l16 = lane & 15;
  const int row0 = blockIdx.x * 128, col0 = blockIdx.y * 64;
  const int wm = (wave >> 1) * 64, wn = (wave & 1) * 32;

  const int ra = tid >> 2, ca = (tid & 3) * 8;  // A chunk mapping (2 chunks: ra, ra+64)
  const u16* Ap0 = A + (size_t)(row0 + ra) * K + ca;
  const u16* Ap1 = A + (size_t)(row0 + ra + 64) * K + ca;
  const u16* Bp  = B + (size_t)(col0 + ra) * K + ca;   // B: 64 rows x 4 chunks

  f32x4 acc[4][2] = {};
  uint4 pa0 = *(const uint4*)(Ap0);
  uint4 pa1 = *(const uint4*)(Ap1);
  uint4 pb  = *(const uint4*)(Bp);

  for (int k0 = 0; k0 < K; k0 += 32) {
    __syncthreads();
    *(uint4*)(&As[ra * LD + ca])        = pa0;
    *(uint4*)(&As[(ra + 64) * LD + ca]) = pa1;
    *(uint4*)(&Bs[ra * LD + ca])        = pb;
    if (k0 + 32 < K) {
      pa0 = *(const uint4*)(Ap0 + k0 + 32);
      pa1 = *(const uint4*)(Ap1 + k0 + 32);
      pb  = *(const uint4*)(Bp + k0 + 32);
    }
    __syncthreads();
    short8 af[4], bfr[2];
    #pragma unroll
    for (int mt = 0; mt < 4; mt++)
      af[mt] = *(const short8*)&As[(wm + mt * 16 + l16) * LD + quad * 8];
    #pragma unroll
    for (int nt = 0; nt < 2; nt++)
      bfr[nt] = *(const short8*)&Bs[(wn + nt * 16 + l16) * LD + quad * 8];
    #pragma unroll
    for (int mt = 0; mt < 4; mt++)
      #pragma unroll
      for (int nt = 0; nt < 2; nt++)
        acc[mt][nt] = __builtin_amdgcn_mfma_f32_16x16x32_bf16(af[mt], bfr[nt], acc[mt][nt], 0, 0, 0);
  }

  float qkscale = 1.f;
  if (MODE == 0) {
    float t = *taup;
    float sp = (t > 20.f) ? t : log1pf(expf(t));
    qkscale = (0.125f / (sp + 1e-6f)) * 1.44269504088896340736f;  // fold log2(e)
  }

  // epilogue: C layout col=lane&15, row=quad*4+reg
  #pragma unroll
  for (int mt = 0; mt < 4; mt++)
  #pragma unroll
  for (int nt = 0; nt < 2; nt++)
  #pragma unroll
  for (int r = 0; r < 4; r++) {
    int gm = row0 + wm + mt * 16 + quad * 4 + r;
    int gn = col0 + wn + nt * 16 + l16;
    float v = acc[mt][nt][r];
    if (MODE == 0) {
      int b = gm >> 11, n = gm & 2047;
      int h = gn >> 6, d = gn & 63;
      out0[(((size_t)(b * NH + h)) * SEQ + n) * 64 + d] = f2bf(v * qkscale);
    } else if (MODE == 1) {
      int b = gm >> 11, n = gm & 2047;
      if (gn < CDIM) {
        int h = gn >> 6, d = gn & 63;
        out0[(((size_t)(b * NH + h)) * SEQ + n) * 64 + d] = f2bf(v);
      } else {
        int c = gn - CDIM;
        int h = c >> 6, d = c & 63;
        // V transposed: [B,H,D,N]
        out1[(((size_t)(b * NH + h)) * 64 + d) * SEQ + n] = f2bf(v);
      }
    } else {
      outf[(size_t)gm * N + gn] = v + bias[gn];
    }
  }
}

// ---------------- flash attention (transposed-S scheme) ----------------
// grid: 48 (b,h) * 16 q-tiles of 128. block 256 = 4 waves, 32 q-rows/wave
// (m = lane&15 within two 16-row subtiles mt=0,1). K/V tile BN=64.
// St = K Q^T so softmax rows live per-lane; P round-trips LDS vectorized.
__global__ __launch_bounds__(256, 3) void attn_kernel(
    const u16* __restrict__ Q, const u16* __restrict__ Kb,
    const u16* __restrict__ Vtg, u16* __restrict__ Ob)
{
  constexpr int LDK = 72;                      // 64 + 8 pad
  __shared__ __align__(16) u16 Ks[64 * LDK];   // [kk][d]
  __shared__ __align__(16) u16 Vs[64 * LDK];   // [d][kk]  (from global-transposed V)
  __shared__ __align__(16) u16 Ps[4 * 16 * LDK]; // per-wave 16 rows [m][kk]

  const int qt = blockIdx.x & 15;
  const int bh = blockIdx.x >> 4;
  const int b = bh / NH, h = bh % NH;
  const u16* Qp = Q   + (size_t)bh * SEQ * 64;
  const u16* Kp = Kb  + (size_t)bh * SEQ * 64;
  const u16* Vp = Vtg + (size_t)bh * 64 * SEQ;

  const int tid = threadIdx.x;
  const int wave = tid >> 6, lane = tid & 63;
  const int quad = lane >> 4, l16 = lane & 15;
  u16* Pw = Ps + wave * 16 * LDK;

  // Q fragments (B-operand): Q[m = l16][d = ks*32+quad*8+j], pre-scaled by qkscale
  short8 qf[2][2];
  #pragma unroll
  for (int mt = 0; mt < 2; mt++)
    #pragma unroll
    for (int ks = 0; ks < 2; ks++)
      qf[mt][ks] = *(const short8*)(Qp + (size_t)(qt * 128 + wave * 32 + mt * 16 + l16) * 64 + ks * 32 + quad * 8);

  // staging mapping: 512 chunks of 8 u16 per matrix, 2 per thread
  const int r0 = tid >> 3, c0 = (tid & 7) * 8;           // chunk 0: row r0
  const int r1 = r0 + 32, c1 = c0;                        // chunk 1: row r0+32
  uint4 kpre0, kpre1, vpre0, vpre1;
  kpre0 = *(const uint4*)(Kp + (size_t)r0 * 64 + c0);
  kpre1 = *(const uint4*)(Kp + (size_t)r1 * 64 + c1);
  vpre0 = *(const uint4*)(Vp + (size_t)r0 * SEQ + c0);
  vpre1 = *(const uint4*)(Vp + (size_t)r1 * SEQ + c1);

  f32x4 oacc[2][4] = {};
  float mrow[2] = {-1e30f, -1e30f}, lrow[2] = {0.f, 0.f};

  for (int kt = 0; kt < SEQ / 64; kt++) {
    __syncthreads();
    *(uint4*)(&Ks[r0 * LDK + c0]) = kpre0;
    *(uint4*)(&Ks[r1 * LDK + c1]) = kpre1;
    *(uint4*)(&Vs[r0 * LDK + c0]) = vpre0;
    *(uint4*)(&Vs[r1 * LDK + c1]) = vpre1;
    if (kt + 1 < SEQ / 64) {
      int nb = (kt + 1) * 64;
      kpre0 = *(const uint4*)(Kp + (size_t)(nb + r0) * 64 + c0);
      kpre1 = *(const uint4*)(Kp + (size_t)(nb + r1) * 64 + c1);
      vpre0 = *(const uint4*)(Vp + (size_t)r0 * SEQ + nb + c0);
      vpre1 = *(const uint4*)(Vp + (size_t)r1 * SEQ + nb + c1);
    }
    __syncthreads();

    // St = K Q^T : sacc[mt][ntk] tile holds St[kk=ntk*16+quad*4+r][m=l16]
    f32x4 sacc[2][4] = {};
    #pragma unroll
    for (int ks = 0; ks < 2; ks++) {
      #pragma unroll
      for (int ntk = 0; ntk < 4; ntk++) {
        short8 kf = *(const short8*)&Ks[(ntk * 16 + l16) * LDK + ks * 32 + quad * 8];
        #pragma unroll
        for (int mt = 0; mt < 2; mt++)
          sacc[mt][ntk] = __builtin_amdgcn_mfma_f32_16x16x32_bf16(kf, qf[mt][ks], sacc[mt][ntk], 0, 0, 0);
      }
    }

    short8 pf[2][2];
    #pragma unroll
    for (int mt = 0; mt < 2; mt++) {
      // within-lane max over 16 values, then reduce across quads (2 shfl)
      float tmax = -1e30f;
      #pragma unroll
      for (int ntk = 0; ntk < 4; ntk++)
        #pragma unroll
        for (int r = 0; r < 4; r++)
          tmax = fmaxf(tmax, sacc[mt][ntk][r]);
      tmax = fmaxf(tmax, __shfl_xor(tmax, 16));
      tmax = fmaxf(tmax, __shfl_xor(tmax, 32));
      float mnew = fmaxf(mrow[mt], tmax);
      float alpha = exp2f(mrow[mt] - mnew);
      mrow[mt] = mnew;

      float rs = 0.f;
      #pragma unroll
      for (int ntk = 0; ntk < 4; ntk++) {
        float p0 = exp2f(sacc[mt][ntk][0] - mnew);
        float p1 = exp2f(sacc[mt][ntk][1] - mnew);
        float p2 = exp2f(sacc[mt][ntk][2] - mnew);
        float p3 = exp2f(sacc[mt][ntk][3] - mnew);
        rs += (p0 + p1) + (p2 + p3);
        u32 lo = ((__float_as_uint(p1) + 0x8000u) & 0xFFFF0000u) | ((__float_as_uint(p0) + 0x8000u) >> 16);
        u32 hi = ((__float_as_uint(p3) + 0x8000u) & 0xFFFF0000u) | ((__float_as_uint(p2) + 0x8000u) >> 16);
        *(uint2*)(&Pw[l16 * LDK + ntk * 16 + quad * 4]) = make_uint2(lo, hi);
      }
      rs += __shfl_xor(rs, 16);
      rs += __shfl_xor(rs, 32);
      lrow[mt] = lrow[mt] * alpha + rs;

      // rescale O rows (oacc rows are m=quad*4+r; alpha lives at m=l16)
      float av[4];
      #pragma unroll
      for (int r = 0; r < 4; r++) av[r] = __shfl(alpha, quad * 4 + r);
      #pragma unroll
      for (int dt = 0; dt < 4; dt++)
        #pragma unroll
        for (int r = 0; r < 4; r++)
          oacc[mt][dt][r] *= av[r];

      // P A-fragments: P[m=l16][kk=ks*32+quad*8+j]
      pf[mt][0] = *(const short8*)&Pw[l16 * LDK + quad * 8];
      pf[mt][1] = *(const short8*)&Pw[l16 * LDK + 32 + quad * 8];
    }

    // O += P V
    #pragma unroll
    for (int ks = 0; ks < 2; ks++)
      #pragma unroll
      for (int dt = 0; dt < 4; dt++) {
        short8 vf = *(const short8*)&Vs[(dt * 16 + l16) * LDK + ks * 32 + quad * 8];
        #pragma unroll
        for (int mt = 0; mt < 2; mt++)
          oacc[mt][dt] = __builtin_amdgcn_mfma_f32_16x16x32_bf16(pf[mt][ks], vf, oacc[mt][dt], 0, 0, 0);
      }
  }

  // epilogue: O / l -> ao[b][n][h*64+d]
  #pragma unroll
  for (int mt = 0; mt < 2; mt++) {
    float lv[4];
    #pragma unroll
    for (int r = 0; r < 4; r++) lv[r] = __shfl(lrow[mt], quad * 4 + r);
    #pragma unroll
    for (int r = 0; r < 4; r++) {
      float inv = 1.0f / lv[r];
      int n = qt * 128 + wave * 32 + mt * 16 + quad * 4 + r;
      size_t base = ((size_t)b * SEQ + n) * CDIM + h * 64;
      #pragma unroll
      for (int dt = 0; dt < 4; dt++)
        Ob[base + dt * 16 + l16] = f2bf(oacc[mt][dt][r] * inv);
    }
  }
}

// ---------------- launch ----------------
extern "C" void kernel_launch(void* const* d_in, const int* in_sizes, int n_in,
                              void* d_out, int out_size, void* d_ws, size_t ws_size,
                              hipStream_t stream)
{
  const float* x     = (const float*)d_in[0];
  const float* y     = (const float*)d_in[1];
  const float* Wq    = (const float*)d_in[2];
  const float* Wkv   = (const float*)d_in[3];
  const float* taup  = (const float*)d_in[4];
  const float* Wproj = (const float*)d_in[5];
  const float* bproj = (const float*)d_in[6];
  float* out = (float*)d_out;

  char* ws = (char*)d_ws;
  size_t off = 0;
  auto alloc = [&](size_t bytes) { char* p = ws + off; off += bytes; return p; };
  u16* xb   = (u16*)alloc(8192ull * 768 * 2);
  u16* yb   = (u16*)alloc(8192ull * 768 * 2);
  u16* wqb  = (u16*)alloc(768ull * 768 * 2);
  u16* wkvb = (u16*)alloc(1536ull * 768 * 2);
  u16* wpb  = (u16*)alloc(768ull * 768 * 2);
  u16* qb   = (u16*)alloc(8192ull * 768 * 2);   // [B,H,N,D] (pre-scaled)
  u16* kb   = (u16*)alloc(8192ull * 768 * 2);   // [B,H,N,D]
  u16* vtb  = (u16*)alloc(8192ull * 768 * 2);   // [B,H,D,N]
  u16* ao   = (u16*)alloc(8192ull * 768 * 2);   // [B,N,C]

  cvt_f32_bf16<<<8192 * 768 / 1024, 256, 0, stream>>>(x, xb, 8192 * 768);
  cvt_f32_bf16<<<8192 * 768 / 1024, 256, 0, stream>>>(y, yb, 8192 * 768);
  cvt_f32_bf16<<<768 * 768 / 1024, 256, 0, stream>>>(Wq, wqb, 768 * 768);
  cvt_f32_bf16<<<1536 * 768 / 1024, 256, 0, stream>>>(Wkv, wkvb, 1536 * 768);
  cvt_f32_bf16<<<768 * 768 / 1024, 256, 0, stream>>>(Wproj, wpb, 768 * 768);

  gemm_nt<0><<<dim3(64, 12), 256, 0, stream>>>(xb, wqb, qb, nullptr, nullptr, nullptr, taup, 8192, 768, 768);
  gemm_nt<1><<<dim3(64, 24), 256, 0, stream>>>(yb, wkvb, kb, vtb, nullptr, nullptr, nullptr, 8192, 1536, 768);
  attn_kernel<<<dim3(48 * 16), 256, 0, stream>>>(qb, kb, vtb, ao);
  gemm_nt<2><<<dim3(64, 12), 256, 0, stream>>>(ao, wpb, nullptr, nullptr, out, bproj, nullptr, 8192, 768, 768);
}